// Round 2
// baseline (171.523 us; speedup 1.0000x reference)
//
#include <hip/hip_runtime.h>
#include <hip/hip_bf16.h>
#include <math.h>

#define EDIM 256
#define HDIM 256
#define BDIM 64
#define TDIM 2048
#define NC   64
#define TC   32
#define CPB  4      // chunks per persistent block

typedef __attribute__((ext_vector_type(8)))  short  short8;
typedef __attribute__((ext_vector_type(4)))  float  floatx4;
typedef __attribute__((ext_vector_type(4)))  unsigned int uintx4;

__device__ __forceinline__ unsigned short f2bf(float f) {
    unsigned int u = __float_as_uint(f);
    u += 0x7FFFu + ((u >> 16) & 1u);      // RNE
    return (unsigned short)(u >> 16);
}
__device__ __forceinline__ unsigned int pk2(float a, float b) {
    return (unsigned int)f2bf(a) | ((unsigned int)f2bf(b) << 16);
}
__device__ __forceinline__ float sigm(float x) {
    return __builtin_amdgcn_rcpf(1.f + __expf(-x));
}
__device__ __forceinline__ float tanh_fast(float x) {
    return fmaf(-2.f, __builtin_amdgcn_rcpf(1.f + __expf(2.f * x)), 1.f);
}

// Pack kernel, three roles by blockIdx:
//  bx < 256            : Wp fragment-pack (unchanged).
//  bx >= 256, mode==2  : gather-materialize Xe[b][cc][ks][th][q][col][8] bf16
//                        = emb[X[b][cc*32+th*16+col]][ks*32+q*8+j], the exact
//                        abuf fragment order -> mfma A reads become coalesced.
//  bx >= 256, mode==1  : emb -> bf16 table (legacy gather path).
__global__ __launch_bounds__(256) void qrnn_pack(
    const float* __restrict__ Wq, const float* __restrict__ emb,
    const int* __restrict__ X,
    unsigned short* __restrict__ Wp, unsigned short* __restrict__ aux,
    int mode)
{
    const int bx = blockIdx.x;
    if (bx < 256) {
        const int nt = (bx >> 3) & 7;
        const int hg = bx >> 6;
        const int ks = bx & 7;
        const int t = threadIdx.x;
        const int lane = t >> 2, pj = t & 3;
        const int col = lane & 15, q = lane >> 4;
        const int h = hg * 64 + (nt & 3) * 16 + col;
        const int c = (nt < 4) ? h : (HDIM + h);
        const int k = ks * 32 + q * 8 + pj * 2;
        unsigned int v = pk2(Wq[k * (3 * HDIM) + c], Wq[(k + 1) * (3 * HDIM) + c]);
        *(unsigned int*)(Wp + (size_t)bx * 512 + lane * 8 + pj * 2) = v;
    } else if (mode == 2) {
        // One block per (b, cc): 32 tokens x 256 e = 16 KB bf16 out.
        const int bx2 = bx - 256;            // 0..4095
        const int b = bx2 >> 6, cc = bx2 & 63;
        __shared__ int tok[TC];
        if (threadIdx.x < TC)
            tok[threadIdx.x] = X[b * TDIM + cc * TC + threadIdx.x];
        __syncthreads();
        unsigned short* xb = aux + (size_t)bx2 * 8192;
#pragma unroll
        for (int r = 0; r < 4; ++r) {
            const int ci = r * 256 + threadIdx.x;       // 16B-chunk index, write-coalesced
            const int col = ci & 15, q = (ci >> 4) & 3;
            const int th = (ci >> 6) & 1, ks = ci >> 7;
            const int t = th * 16 + col;
            const float* src = emb + (size_t)tok[t] * EDIM + ks * 32 + q * 8;
            floatx4 a = *(const floatx4*)src;
            floatx4 c4 = *(const floatx4*)(src + 4);
            uintx4 o = {pk2(a.x, a.y), pk2(a.z, a.w), pk2(c4.x, c4.y), pk2(c4.z, c4.w)};
            *(uintx4*)(xb + (size_t)ci * 8) = o;
        }
    } else {
        size_t i = ((size_t)(bx - 256) * 256 + threadIdx.x) * 8;
        floatx4 a = *(const floatx4*)(emb + i);
        floatx4 b = *(const floatx4*)(emb + i + 4);
        uintx4 o = {pk2(a.x, a.y), pk2(a.z, a.w), pk2(b.x, b.y), pk2(b.z, b.w)};
        *(uintx4*)(aux + i) = o;
    }
}

// Main: persistent block = 4 chunks x 8 batches x 64 h (128 n-cols).
// B (weights) staged to LDS ONCE per block; chunk loop is barrier-free.
// MODE 2: A read as coalesced short8 streams from materialized Xe.
// MODE 1: A gathered per-lane from bf16 emb table.  MODE 0: from f32 emb.
// 3-slot (2-ahead) software pipeline crosses chunk boundaries.
// Note: 3-D grid linear id = cg + 16*(bg + 8*hg) -> the 4 hg siblings of one
// (cg,bg) share an XCD (stride 128 % 8 == 0), so MODE-2 redundant A reads L2-hit.
template<int MODE>
__global__ __launch_bounds__(256, 2) void qrnn_mfma(
    const int* __restrict__ X, const float* __restrict__ emb,
    const unsigned short* __restrict__ aux, const unsigned short* __restrict__ Wp,
    const float* __restrict__ bq, float* __restrict__ wsA, float* __restrict__ wsB)
{
    __shared__ __align__(16) short Bsh[32768];   // 64 KB: [nt][ks][64 lanes][8]

    const int tid = threadIdx.x;
    const int cg = blockIdx.x, bg = blockIdx.y, hg = blockIdx.z;
    const int lane = tid & 63, w = tid >> 6;
    const int col = lane & 15, q = lane >> 4;

    // Stage B slice (64 KB, all ks) once.
    const unsigned short* wpb = Wp + (size_t)hg * 32768;
#pragma unroll
    for (int i = 0; i < 16; ++i) {
        const int ch = w * 16 + i;          // wave-uniform
        __builtin_amdgcn_global_load_lds(
            (const __attribute__((address_space(1))) unsigned int*)(wpb + ch * 512 + lane * 8),
            (__attribute__((address_space(3))) unsigned int*)(Bsh + ch * 512),
            16, 0, 0);
    }

    const int b0 = bg * 8 + 2 * w;
    int xid[CPB][4];
    if constexpr (MODE < 2) {
#pragma unroll
        for (int c = 0; c < CPB; ++c)
#pragma unroll
            for (int mt = 0; mt < 4; ++mt)
                xid[c][mt] = X[(b0 + (mt >> 1)) * TDIM + (cg * CPB + c) * TC + (mt & 1) * 16 + col];
    }

    const int hbase = hg * 64;
    float bz[4], bff[4];
#pragma unroll
    for (int nt = 0; nt < 4; ++nt) {
        bz[nt]  = bq[hbase + nt * 16 + col];
        bff[nt] = bq[HDIM + hbase + nt * 16 + col];
    }

    short8 abuf[3][4];
    auto fetchA = [&](int c, int ks, int slot) {
#pragma unroll
        for (int mt = 0; mt < 4; ++mt) {
            if constexpr (MODE == 2) {
                const size_t bb = (size_t)(b0 + (mt >> 1)) * NC + (cg * CPB + c);
                abuf[slot][mt] = *(const short8*)(aux + ((bb * 8 + ks) * 2 + (mt & 1)) * 512 + lane * 8);
            } else if constexpr (MODE == 1) {
                abuf[slot][mt] = *(const short8*)(aux + (size_t)xid[c][mt] * EDIM + q * 8 + ks * 32);
            } else {
                const float* ap = emb + (size_t)xid[c][mt] * EDIM + q * 8 + ks * 32;
                floatx4 f0 = *(const floatx4*)ap;
                floatx4 f1 = *(const floatx4*)(ap + 4);
                uintx4 p = {pk2(f0.x, f0.y), pk2(f0.z, f0.w),
                            pk2(f1.x, f1.y), pk2(f1.z, f1.w)};
                abuf[slot][mt] = *(short8*)&p;
            }
        }
    };

    floatx4 acc[4][8];
#pragma unroll
    for (int mt = 0; mt < 4; ++mt)
#pragma unroll
        for (int nt = 0; nt < 8; ++nt) acc[mt][nt] = (floatx4){0.f, 0.f, 0.f, 0.f};

    fetchA(0, 0, 0);
    fetchA(0, 1, 1);
    __syncthreads();   // waits staging vmem too

#pragma unroll
    for (int c = 0; c < CPB; ++c) {
#pragma unroll
        for (int ks = 0; ks < 8; ++ks) {
            const int s = c * 8 + ks;
            if (s + 2 < CPB * 8)
                fetchA((s + 2) >> 3, (s + 2) & 7, (s + 2) % 3);
            short8 bf[8];
#pragma unroll
            for (int nt = 0; nt < 8; ++nt)
                bf[nt] = *(const short8*)(Bsh + (nt * 8 + ks) * 512 + lane * 8);
            const int sl = s % 3;
#pragma unroll
            for (int nt = 0; nt < 8; ++nt)
#pragma unroll
                for (int mt = 0; mt < 4; ++mt)
                    acc[mt][nt] = __builtin_amdgcn_mfma_f32_16x16x32_bf16(abuf[sl][mt], bf[nt], acc[mt][nt], 0, 0, 0);
        }

        // Epilogue for chunk cc: t = q*4 + j (+16*(mt&1)), h-col = nt*16+col.
        const int cc = cg * CPB + c;
        float Af0[4], Bf0[4], Af1[4], Bf1[4];
#pragma unroll
        for (int nt = 0; nt < 4; ++nt) {
            float Aseg[4], Bseg[4];
#pragma unroll
            for (int mt = 0; mt < 4; ++mt) {
                float Ac = 1.f, Bc = 0.f;
#pragma unroll
                for (int j = 0; j < 4; ++j) {
                    float z = tanh_fast(acc[mt][nt][j] + bz[nt]);
                    float f = sigm(acc[mt][nt + 4][j] + bff[nt]);
                    Ac = f * Ac;
                    Bc = fmaf(f, Bc, (1.f - f) * z);
                }
                Aseg[mt] = Ac; Bseg[mt] = Bc;
            }
#pragma unroll
            for (int st = 0; st < 2; ++st) {
                const int msk = 16 << st;
                const bool self_earlier = ((q >> st) & 1) == 0;
#pragma unroll
                for (int mt = 0; mt < 4; ++mt) {
                    float Ap = __shfl_xor(Aseg[mt], msk, 64);
                    float Bp = __shfl_xor(Bseg[mt], msk, 64);
                    Bseg[mt] = self_earlier ? fmaf(Ap, Bseg[mt], Bp)
                                            : fmaf(Aseg[mt], Bp, Bseg[mt]);
                    Aseg[mt] = Aseg[mt] * Ap;
                }
            }
            Af0[nt] = Aseg[0] * Aseg[1];
            Bf0[nt] = fmaf(Aseg[1], Bseg[0], Bseg[1]);
            Af1[nt] = Aseg[2] * Aseg[3];
            Bf1[nt] = fmaf(Aseg[3], Bseg[2], Bseg[3]);
        }

        float As0 = (q == 0) ? Af0[0] : (q == 1) ? Af0[1] : (q == 2) ? Af0[2] : Af0[3];
        float Bs0 = (q == 0) ? Bf0[0] : (q == 1) ? Bf0[1] : (q == 2) ? Bf0[2] : Bf0[3];
        float As1 = (q == 0) ? Af1[0] : (q == 1) ? Af1[1] : (q == 2) ? Af1[2] : Af1[3];
        float Bs1 = (q == 0) ? Bf1[0] : (q == 1) ? Bf1[1] : (q == 2) ? Bf1[2] : Bf1[3];

        const size_t r0 = ((size_t)cc * BDIM + b0) * HDIM + hbase + lane;
        wsA[r0] = As0;          wsB[r0] = Bs0;
        wsA[r0 + HDIM] = As1;   wsB[r0 + HDIM] = Bs1;

#pragma unroll
        for (int mt = 0; mt < 4; ++mt)
#pragma unroll
            for (int nt = 0; nt < 8; ++nt) acc[mt][nt] = (floatx4){0.f, 0.f, 0.f, 0.f};
    }
}

// Combine chunk (A,B) pairs + o-gate at t=T-1 + output dot.
__global__ __launch_bounds__(256) void qrnn_combine(
    const float* __restrict__ wsA, const float* __restrict__ wsB,
    const float* __restrict__ c0, const int* __restrict__ X,
    const float* __restrict__ emb, const float* __restrict__ Wq,
    const float* __restrict__ bq, const float* __restrict__ Wout,
    const float* __restrict__ bout, float* __restrict__ out)
{
    const int b = blockIdx.x;
    const int h = threadIdx.x;

    float c = c0[b * HDIM + h];
    for (int c8 = 0; c8 < NC; c8 += 8) {
        float a[8], bb[8];
#pragma unroll
        for (int i = 0; i < 8; ++i) {
            size_t base = ((size_t)(c8 + i) * BDIM + b) * HDIM + h;
            a[i]  = wsA[base];
            bb[i] = wsB[base];
        }
#pragma unroll
        for (int i = 0; i < 8; ++i) c = fmaf(a[i], c, bb[i]);
    }

    __shared__ float xs[EDIM];
    int idx = X[b * TDIM + (TDIM - 1)];
    xs[h] = emb[(size_t)idx * EDIM + h];
    __syncthreads();

    float acc = 0.f;
#pragma unroll 16
    for (int e = 0; e < EDIM; ++e)
        acc = fmaf(xs[e], Wq[e * (3 * HDIM) + 2 * HDIM + h], acc);

    float o  = 1.f / (1.f + expf(-(acc + bq[2 * HDIM + h])));
    float hn = o * c;

    __shared__ float red[HDIM];
    red[h] = hn * Wout[h];
    __syncthreads();
    for (int s = HDIM / 2; s > 0; s >>= 1) {
        if (h < s) red[h] += red[h + s];
        __syncthreads();
    }
    if (h == 0) out[b] = red[0] + bout[0];
}

extern "C" void kernel_launch(void* const* d_in, const int* in_sizes, int n_in,
                              void* d_out, int out_size, void* d_ws, size_t ws_size,
                              hipStream_t stream) {
    const int*   X    = (const int*)d_in[0];
    const float* emb  = (const float*)d_in[1];
    const float* Wq   = (const float*)d_in[2];
    const float* bq   = (const float*)d_in[3];
    const float* c0   = (const float*)d_in[4];
    const float* Wout = (const float*)d_in[5];
    const float* bout = (const float*)d_in[6];
    float* out = (float*)d_out;

    float* wsA = (float*)d_ws;                        // [NC][B][H]
    float* wsB = wsA + (size_t)NC * BDIM * HDIM;      // [NC][B][H]
    unsigned short* Wp  = (unsigned short*)(wsB + (size_t)NC * BDIM * HDIM);  // 256 KB
    unsigned short* aux = Wp + (size_t)256 * 512;     // Xe (67.1 MB) or ebf (16.4 MB)

    const size_t wsAB = (size_t)2 * NC * BDIM * HDIM * 4;
    const size_t wpsz = (size_t)256 * 512 * 2;
    const size_t need2 = wsAB + wpsz + (size_t)BDIM * TDIM * EDIM * 2;   // ~75.8 MB
    const size_t need1 = wsAB + wpsz + (size_t)32000 * EDIM * 2;         // ~25.0 MB
    const int mode = (ws_size >= need2) ? 2 : (ws_size >= need1 ? 1 : 0);

    const int gather_blocks = (mode == 2) ? (BDIM * NC)          // 4096
                            : (mode == 1) ? (32000 * EDIM / 8) / 256   // 4000
                            : 0;
    qrnn_pack<<<256 + gather_blocks, 256, 0, stream>>>(Wq, emb, X, Wp, aux, mode);

    dim3 g(NC / CPB, BDIM / 8, HDIM / 64);   // 16 x 8 x 4 = 512 blocks (2/CU)
    if      (mode == 2) qrnn_mfma<2><<<g, 256, 0, stream>>>(X, emb, aux, Wp, bq, wsA, wsB);
    else if (mode == 1) qrnn_mfma<1><<<g, 256, 0, stream>>>(X, emb, aux, Wp, bq, wsA, wsB);
    else                qrnn_mfma<0><<<g, 256, 0, stream>>>(X, emb, aux, Wp, bq, wsA, wsB);

    qrnn_combine<<<BDIM, 256, 0, stream>>>(wsA, wsB, c0, X, emb, Wq, bq, Wout, bout, out);
}